// Round 1
// baseline (39.712 us; speedup 1.0000x reference)
//
#include <hip/hip_runtime.h>

// Problem constants (match reference): R=16, E=4096, N=262144.
// loss = -sum_i [ lab_i*sig(x_i) + (1-lab_i)*(1-sig(x_i)) ] / ((1+neg)*N)
// with x_i = pv[rel_i, e1_i, e2_i], neg = #(labels==0).
// Note 1-sigmoid(x) = sigmoid(-x), so term_i = sigmoid(lab_i ? x_i : -x_i).

__global__ void zero_ws_kernel(float* ws) {
    ws[0] = 0.0f;                 // float total accumulator
    reinterpret_cast<int*>(ws)[1] = 0;  // int negative-count accumulator
}

__global__ __launch_bounds__(256) void loss_main_kernel(
        const float* __restrict__ pv,
        const int* __restrict__ rel_idx,
        const int* __restrict__ e1_idx,
        const int* __restrict__ e2_idx,
        const int* __restrict__ labels,
        float* __restrict__ ws,
        int n) {
    int i = blockIdx.x * blockDim.x + threadIdx.x;

    float term = 0.0f;
    int negc = 0;
    if (i < n) {
        int r = rel_idx[i];
        int a = e1_idx[i];
        int b = e2_idx[i];
        int L = labels[i];
        // E = 4096 = 2^12, indices in [0, 4096): pack with shifts/ORs.
        size_t idx = ((((size_t)r << 12) | (size_t)a) << 12) | (size_t)b;
        float x = pv[idx];
        // term = L ? sigmoid(x) : 1 - sigmoid(x) = sigmoid(L ? x : -x)
        float sx = L ? -x : x;          // sigmoid(x) = 1/(1+exp(-x))
        term = 1.0f / (1.0f + expf(sx));
        negc = (L == 0) ? 1 : 0;
    }

    // Wave (64-lane) butterfly-free down-shuffle reduction.
    #pragma unroll
    for (int off = 32; off > 0; off >>= 1) {
        term += __shfl_down(term, off, 64);
        negc += __shfl_down(negc, off, 64);
    }

    __shared__ float sterm[4];
    __shared__ int   sneg[4];
    int lane = threadIdx.x & 63;
    int wid  = threadIdx.x >> 6;
    if (lane == 0) { sterm[wid] = term; sneg[wid] = negc; }
    __syncthreads();

    if (threadIdx.x == 0) {
        float t = sterm[0] + sterm[1] + sterm[2] + sterm[3];
        int   c = sneg[0] + sneg[1] + sneg[2] + sneg[3];
        atomicAdd(ws, t);
        atomicAdd(reinterpret_cast<int*>(ws) + 1, c);
    }
}

__global__ void finalize_kernel(const float* __restrict__ ws,
                                float* __restrict__ out, int n) {
    double total = (double)ws[0];
    double neg   = (double)reinterpret_cast<const int*>(ws)[1];
    out[0] = (float)(-total / ((1.0 + neg) * (double)n));
}

extern "C" void kernel_launch(void* const* d_in, const int* in_sizes, int n_in,
                              void* d_out, int out_size, void* d_ws, size_t ws_size,
                              hipStream_t stream) {
    const float* pv      = (const float*)d_in[0];
    const int*   rel_idx = (const int*)d_in[1];
    const int*   e1_idx  = (const int*)d_in[2];
    const int*   e2_idx  = (const int*)d_in[3];
    const int*   labels  = (const int*)d_in[4];
    float* out = (float*)d_out;
    float* ws  = (float*)d_ws;

    int n = in_sizes[1];  // N = 262144 triplets

    zero_ws_kernel<<<1, 1, 0, stream>>>(ws);
    int block = 256;
    int grid = (n + block - 1) / block;  // 1024 blocks
    loss_main_kernel<<<grid, block, 0, stream>>>(pv, rel_idx, e1_idx, e2_idx,
                                                 labels, ws, n);
    finalize_kernel<<<1, 1, 0, stream>>>(ws, out, n);
}

// Round 5
// 11.634 us; speedup vs baseline: 3.4135x; 3.4135x over previous
//
#include <hip/hip_runtime.h>

// R=16, E=4096, N=262144.
// loss = -sum_i sigmoid(lab_i ? x_i : -x_i) / ((1+neg)*N),
// x_i = pv[rel_i*E*E + e1_i*E + e2_i], neg = #(labels==0).
//
// Structure: 2 kernels, no atomics, no ws pre-zero needed.
//  K1: 256 blocks x 256 threads, 4 triplets/thread (int4 index loads,
//      4 independent gathers in flight), block reduce -> ws partials.
//  K2: 1 block x 256 threads reduces the 256 partials, writes loss.

#define NBLK 256

__global__ __launch_bounds__(256) void loss_partial_kernel(
        const float* __restrict__ pv,
        const int* __restrict__ rel_idx,
        const int* __restrict__ e1_idx,
        const int* __restrict__ e2_idx,
        const int* __restrict__ labels,
        float* __restrict__ ws_sum,   // [NBLK]
        int*   __restrict__ ws_neg) { // [NBLK]
    int t = blockIdx.x * blockDim.x + threadIdx.x;  // 0..65535

    // Vector loads of 4 consecutive indices per array (16B aligned).
    int4 r4 = reinterpret_cast<const int4*>(rel_idx)[t];
    int4 a4 = reinterpret_cast<const int4*>(e1_idx)[t];
    int4 b4 = reinterpret_cast<const int4*>(e2_idx)[t];
    int4 L4 = reinterpret_cast<const int4*>(labels)[t];

    // 4 independent gathers (ILP) — E=4096=2^12 pack with shifts.
    const int* rp = &r4.x; const int* ap = &a4.x;
    const int* bp = &b4.x; const int* Lp = &L4.x;
    float x[4];
    #pragma unroll
    for (int k = 0; k < 4; ++k) {
        size_t idx = ((((size_t)rp[k] << 12) | (size_t)ap[k]) << 12) | (size_t)bp[k];
        x[k] = pv[idx];
    }

    float term = 0.0f;
    int negc = 0;
    #pragma unroll
    for (int k = 0; k < 4; ++k) {
        float sx = Lp[k] ? -x[k] : x[k];
        term += 1.0f / (1.0f + expf(sx));   // sigmoid(L ? x : -x)
        negc += (Lp[k] == 0) ? 1 : 0;
    }

    // Wave-64 reduction.
    #pragma unroll
    for (int off = 32; off > 0; off >>= 1) {
        term += __shfl_down(term, off, 64);
        negc += __shfl_down(negc, off, 64);
    }

    __shared__ float sterm[4];
    __shared__ int   sneg[4];
    int lane = threadIdx.x & 63;
    int wid  = threadIdx.x >> 6;
    if (lane == 0) { sterm[wid] = term; sneg[wid] = negc; }
    __syncthreads();

    if (threadIdx.x == 0) {
        ws_sum[blockIdx.x] = sterm[0] + sterm[1] + sterm[2] + sterm[3];
        ws_neg[blockIdx.x] = sneg[0] + sneg[1] + sneg[2] + sneg[3];
    }
}

__global__ __launch_bounds__(256) void loss_final_kernel(
        const float* __restrict__ ws_sum,
        const int*   __restrict__ ws_neg,
        float* __restrict__ out, int n) {
    float term = ws_sum[threadIdx.x];
    int   negc = ws_neg[threadIdx.x];
    #pragma unroll
    for (int off = 32; off > 0; off >>= 1) {
        term += __shfl_down(term, off, 64);
        negc += __shfl_down(negc, off, 64);
    }
    __shared__ float sterm[4];
    __shared__ int   sneg[4];
    int lane = threadIdx.x & 63;
    int wid  = threadIdx.x >> 6;
    if (lane == 0) { sterm[wid] = term; sneg[wid] = negc; }
    __syncthreads();
    if (threadIdx.x == 0) {
        double total = (double)(sterm[0] + sterm[1] + sterm[2] + sterm[3]);
        double neg   = (double)(sneg[0] + sneg[1] + sneg[2] + sneg[3]);
        out[0] = (float)(-total / ((1.0 + neg) * (double)n));
    }
}

extern "C" void kernel_launch(void* const* d_in, const int* in_sizes, int n_in,
                              void* d_out, int out_size, void* d_ws, size_t ws_size,
                              hipStream_t stream) {
    const float* pv      = (const float*)d_in[0];
    const int*   rel_idx = (const int*)d_in[1];
    const int*   e1_idx  = (const int*)d_in[2];
    const int*   e2_idx  = (const int*)d_in[3];
    const int*   labels  = (const int*)d_in[4];
    float* out = (float*)d_out;

    float* ws_sum = (float*)d_ws;
    int*   ws_neg = (int*)((char*)d_ws + NBLK * sizeof(float));

    int n = in_sizes[1];  // N = 262144

    loss_partial_kernel<<<NBLK, 256, 0, stream>>>(pv, rel_idx, e1_idx, e2_idx,
                                                  labels, ws_sum, ws_neg);
    loss_final_kernel<<<1, 256, 0, stream>>>(ws_sum, ws_neg, out, n);
}